// Round 7
// baseline (102.725 us; speedup 1.0000x reference)
//
#include <hip/hip_runtime.h>

typedef unsigned int u32;
typedef unsigned long long u64;

// groups of 4 f32 elements per scale (total elems = cells*85, all %4==0)
#define NG0 5891520u   // 16*76*76*3*85/4
#define NG1 1472880u
#define NG2 368220u
#define NBLK 2048u

struct BlockAcc {            // 96 B
  float sn[3], sc[3], sf[3], sb[3];
  u32   nn[3], np[3], mi[3], pad[3];
};

__device__ __forceinline__ void neg_body(const float4 pv, const float4 gv,
                                         const int4 mv, float& sn, u32& nn)
{
  float d;
  d = gv.x - pv.x; sn = fmaf(d * d, (float)mv.x, sn); nn += (u32)mv.x;
  d = gv.y - pv.y; sn = fmaf(d * d, (float)mv.y, sn); nn += (u32)mv.y;
  d = gv.z - pv.z; sn = fmaf(d * d, (float)mv.z, sn); nn += (u32)mv.z;
  d = gv.w - pv.w; sn = fmaf(d * d, (float)mv.w, sn); nn += (u32)mv.w;
}

// slow path: full per-element pos handling for one 4-elem group (rare)
__device__ __forceinline__ void pos_group(
    const float4 pv, const float4 gv, u32 base, const int* __restrict__ mpos,
    float& sc, float& sf, float& sb, u32& np, u32& mi)
{
  u32 cell = base / 85u;
  u32 ch = base - cell * 85u;
  float ps[4] = {pv.x, pv.y, pv.z, pv.w};
  float gs[4] = {gv.x, gv.y, gv.z, gv.w};
  #pragma unroll
  for (int j = 0; j < 4; ++j) {
    if (mpos[cell] != 0) {
      float x = ps[j], z = gs[j], d = z - x;
      if (ch == 0u) { np++; mi = cell > mi ? cell : mi; }
      if (ch < 4u)       sc += d * d;
      else if (ch == 4u) sf += d * d;
      else               sb += fmaxf(x, 0.f) - x * z + __logf(1.f + __expf(-fabsf(x)));
    }
    ++ch;
    if (ch == 85u) { ch = 0u; ++cell; }
  }
}

// stream one scale: branchless neg + __any-gated inline pos
__device__ __forceinline__ void scale_stream(
    const float* __restrict__ pred, const float* __restrict__ gt,
    const int* __restrict__ mpos, const int* __restrict__ mneg,
    u32 n, u32 tid, u32 stride,
    float& sn, u32& nn, float& sc, float& sf, float& sb, u32& np, u32& mi)
{
  const float4* __restrict__ p4 = (const float4*)pred;
  const float4* __restrict__ g4 = (const float4*)gt;
  const int4*   __restrict__ m4 = (const int4*)mneg;
  const u32 iters = n / stride;   // uniform counted loop
  u32 i = 0;
  for (; i + 2 <= iters; i += 2) {
    u32 ga = tid + i * stride, gb = ga + stride;
    float4 pa = p4[ga], qa = g4[ga]; int4 ma = m4[ga];
    float4 pb = p4[gb], qb = g4[gb]; int4 mb = m4[gb];
    neg_body(pa, qa, ma, sn, nn);
    neg_body(pb, qb, mb, sn, nn);
    // wave-uniform pos gate: 4-elem group spans at most 2 cells
    u32 basea = ga * 4u, baseb = gb * 4u;
    u32 ca0 = basea / 85u, ca1 = (basea + 3u) / 85u;
    u32 cb0 = baseb / 85u, cb1 = (baseb + 3u) / 85u;
    int anyp = mpos[ca0] | mpos[ca1] | mpos[cb0] | mpos[cb1];
    if (__any(anyp != 0)) {          // ~6% of wave-iterations
      pos_group(pa, qa, basea, mpos, sc, sf, sb, np, mi);
      pos_group(pb, qb, baseb, mpos, sc, sf, sb, np, mi);
    }
  }
  for (; i < iters; ++i) {
    u32 ga = tid + i * stride;
    float4 pa = p4[ga], qa = g4[ga]; int4 ma = m4[ga];
    neg_body(pa, qa, ma, sn, nn);
    pos_group(pa, qa, ga * 4u, mpos, sc, sf, sb, np, mi);  // per-lane check
  }
  u32 gl = tid + iters * stride;
  if (gl < n) {
    float4 pa = p4[gl], qa = g4[gl]; int4 ma = m4[gl];
    neg_body(pa, qa, ma, sn, nn);
    pos_group(pa, qa, gl * 4u, mpos, sc, sf, sb, np, mi);
  }
}

__global__ __launch_bounds__(256) void yolo_all(
    const float* __restrict__ pred0, const float* __restrict__ gt0,
    const int* __restrict__ mp0, const int* __restrict__ mn0,
    const float* __restrict__ pred1, const float* __restrict__ gt1,
    const int* __restrict__ mp1, const int* __restrict__ mn1,
    const float* __restrict__ pred2, const float* __restrict__ gt2,
    const int* __restrict__ mp2, const int* __restrict__ mn2,
    BlockAcc* __restrict__ ws)
{
  const u32 tid = blockIdx.x * blockDim.x + threadIdx.x;
  const u32 stride = gridDim.x * blockDim.x;

  float sn0 = 0.f, sc0 = 0.f, sf0 = 0.f, sb0 = 0.f; u32 nn0 = 0, np0 = 0, mi0 = 0;
  float sn1 = 0.f, sc1 = 0.f, sf1 = 0.f, sb1 = 0.f; u32 nn1 = 0, np1 = 0, mi1 = 0;
  float sn2 = 0.f, sc2 = 0.f, sf2 = 0.f, sb2 = 0.f; u32 nn2 = 0, np2 = 0, mi2 = 0;

  scale_stream(pred0, gt0, mp0, mn0, NG0, tid, stride, sn0, nn0, sc0, sf0, sb0, np0, mi0);
  scale_stream(pred1, gt1, mp1, mn1, NG1, tid, stride, sn1, nn1, sc1, sf1, sb1, np1, mi1);
  scale_stream(pred2, gt2, mp2, mn2, NG2, tid, stride, sn2, nn2, sc2, sf2, sb2, np2, mi2);

  // ---- block reduce: 12 float + 9 u32 accumulators ----
  float fs[12] = {sn0, sn1, sn2, sc0, sc1, sc2, sf0, sf1, sf2, sb0, sb1, sb2};
  u32   us[9]  = {nn0, nn1, nn2, np0, np1, np2, mi0, mi1, mi2};
  #pragma unroll
  for (int o = 32; o > 0; o >>= 1) {
    #pragma unroll
    for (int k = 0; k < 12; ++k) fs[k] += __shfl_down(fs[k], o);
    #pragma unroll
    for (int k = 0; k < 6; ++k)  us[k] += __shfl_down((int)us[k], o);
    #pragma unroll
    for (int k = 6; k < 9; ++k) {
      u32 om = __shfl_down((int)us[k], o);
      us[k] = om > us[k] ? om : us[k];
    }
  }
  __shared__ float shf[12][4];
  __shared__ u32   shu[9][4];
  const int wave = threadIdx.x >> 6, lane = threadIdx.x & 63;
  if (lane == 0) {
    #pragma unroll
    for (int k = 0; k < 12; ++k) shf[k][wave] = fs[k];
    #pragma unroll
    for (int k = 0; k < 9; ++k)  shu[k][wave] = us[k];
  }
  __syncthreads();
  if (threadIdx.x == 0) {
    BlockAcc a = {};
    #pragma unroll
    for (int w = 0; w < 4; ++w) {
      #pragma unroll
      for (int s = 0; s < 3; ++s) {
        a.sn[s] += shf[0 + s][w]; a.sc[s] += shf[3 + s][w];
        a.sf[s] += shf[6 + s][w]; a.sb[s] += shf[9 + s][w];
        a.nn[s] += shu[0 + s][w]; a.np[s] += shu[3 + s][w];
        a.mi[s] = shu[6 + s][w] > a.mi[s] ? shu[6 + s][w] : a.mi[s];
      }
    }
    ws[blockIdx.x] = a;
  }
}

__global__ __launch_bounds__(256) void yolo_final(
    const BlockAcc* __restrict__ ws,
    const float* __restrict__ mod0, const float* __restrict__ mod1,
    const float* __restrict__ mod2, float* __restrict__ out)
{
  float fs[12] = {};
  u32   us[9]  = {};
  for (u32 t = threadIdx.x; t < NBLK; t += 256u) {
    const BlockAcc a = ws[t];
    #pragma unroll
    for (int s = 0; s < 3; ++s) {
      fs[0 + s] += a.sn[s]; fs[3 + s] += a.sc[s];
      fs[6 + s] += a.sf[s]; fs[9 + s] += a.sb[s];
      us[0 + s] += a.nn[s]; us[3 + s] += a.np[s];
      us[6 + s] = a.mi[s] > us[6 + s] ? a.mi[s] : us[6 + s];
    }
  }
  #pragma unroll
  for (int o = 32; o > 0; o >>= 1) {
    #pragma unroll
    for (int k = 0; k < 12; ++k) fs[k] += __shfl_down(fs[k], o);
    #pragma unroll
    for (int k = 0; k < 6; ++k)  us[k] += __shfl_down((int)us[k], o);
    #pragma unroll
    for (int k = 6; k < 9; ++k) {
      u32 om = __shfl_down((int)us[k], o);
      us[k] = om > us[k] ? om : us[k];
    }
  }
  __shared__ float shf[12][4];
  __shared__ u32   shu[9][4];
  const int wave = threadIdx.x >> 6, lane = threadIdx.x & 63;
  if (lane == 0) {
    #pragma unroll
    for (int k = 0; k < 12; ++k) shf[k][wave] = fs[k];
    #pragma unroll
    for (int k = 0; k < 9; ++k)  shu[k][wave] = us[k];
  }
  __syncthreads();
  if (threadIdx.x == 0) {
    float F[12]; u32 U[9];
    #pragma unroll
    for (int k = 0; k < 12; ++k) F[k] = shf[k][0] + shf[k][1] + shf[k][2] + shf[k][3];
    #pragma unroll
    for (int k = 0; k < 6; ++k)  U[k] = shu[k][0] + shu[k][1] + shu[k][2] + shu[k][3];
    #pragma unroll
    for (int k = 6; k < 9; ++k) {
      u32 m = shu[k][0];
      m = shu[k][1] > m ? shu[k][1] : m;
      m = shu[k][2] > m ? shu[k][2] : m;
      U[k] = shu[k][3] > m ? shu[k][3] : m;
    }
    const float* mods[3] = {mod0, mod1, mod2};
    float loss = 0.f;
    #pragma unroll
    for (int s = 0; s < 3; ++s) {
      if (U[3 + s] > 0u) {
        float w_last = mods[s][(size_t)U[6 + s] * 6u];  // modulus[...,0] at idx_last
        loss += (w_last * F[3 + s] + F[6 + s] + F[9 + s] * (1.f / 80.f)) / (float)U[3 + s];
      }
      if (U[0 + s] > 0u) loss += 3.0f * F[0 + s] / (float)U[0 + s];
    }
    out[0] = loss;
  }
}

extern "C" void kernel_launch(void* const* d_in, const int* in_sizes, int n_in,
                              void* d_out, int out_size, void* d_ws, size_t ws_size,
                              hipStream_t stream)
{
  const float* pred0 = (const float*)d_in[0];
  const float* gt0   = (const float*)d_in[1];
  const float* mod0  = (const float*)d_in[2];
  const int*   mp0   = (const int*)d_in[3];
  const int*   mn0   = (const int*)d_in[4];
  const float* pred1 = (const float*)d_in[5];
  const float* gt1   = (const float*)d_in[6];
  const float* mod1  = (const float*)d_in[7];
  const int*   mp1   = (const int*)d_in[8];
  const int*   mn1   = (const int*)d_in[9];
  const float* pred2 = (const float*)d_in[10];
  const float* gt2   = (const float*)d_in[11];
  const float* mod2  = (const float*)d_in[12];
  const int*   mp2   = (const int*)d_in[13];
  const int*   mn2   = (const int*)d_in[14];

  BlockAcc* ws = (BlockAcc*)d_ws;   // 2048 * 96 B = 192 KB, every slot written

  yolo_all<<<NBLK, 256, 0, stream>>>(pred0, gt0, mp0, mn0,
                                     pred1, gt1, mp1, mn1,
                                     pred2, gt2, mp2, mn2, ws);
  yolo_final<<<1, 256, 0, stream>>>(ws, mod0, mod1, mod2, (float*)d_out);
}

// Round 8
// 82.507 us; speedup vs baseline: 1.2450x; 1.2450x over previous
//
#include <hip/hip_runtime.h>

typedef unsigned int u32;

// elements per scale = B*g*g*A*85
#define NE0 23566080u   // 16*76*76*3*85
#define NE1 5891520u    // 16*38*38*3*85
#define NE2 1472880u    // 16*19*19*3*85
#define NBLK 2048u

struct ScaleAcc {
  float sum_coord, sum_conf, sum_bce, sum_neg;
  u32 n_pos, n_neg, max_idx, pad;
};

// Block-level reduce, then ONE plain store per block (no atomics: 43k
// same-line device-scope atomic RMWs serialized at the coherence point were
// the 452us critical path in R2).
__device__ __forceinline__ void reduce_and_commit(
    float sc, float sf, float sb, float sn, u32 np, u32 nn, u32 mi,
    ScaleAcc* __restrict__ slot)
{
  #pragma unroll
  for (int o = 32; o > 0; o >>= 1) {
    sc += __shfl_down(sc, o);
    sf += __shfl_down(sf, o);
    sb += __shfl_down(sb, o);
    sn += __shfl_down(sn, o);
    np += __shfl_down(np, o);
    nn += __shfl_down(nn, o);
    u32 omi = __shfl_down(mi, o);
    mi = omi > mi ? omi : mi;
  }
  __shared__ float shf[4][4];
  __shared__ u32 shu[3][4];
  const int wave = threadIdx.x >> 6;
  const int lane = threadIdx.x & 63;
  if (lane == 0) {
    shf[0][wave] = sc; shf[1][wave] = sf; shf[2][wave] = sb; shf[3][wave] = sn;
    shu[0][wave] = np; shu[1][wave] = nn; shu[2][wave] = mi;
  }
  __syncthreads();
  if (threadIdx.x == 0) {
    ScaleAcc a = {0.f, 0.f, 0.f, 0.f, 0u, 0u, 0u, 0u};
    #pragma unroll
    for (int w = 0; w < 4; ++w) {
      a.sum_coord += shf[0][w]; a.sum_conf += shf[1][w];
      a.sum_bce   += shf[2][w]; a.sum_neg  += shf[3][w];
      a.n_pos += shu[0][w]; a.n_neg += shu[1][w];
      a.max_idx = shu[2][w] > a.max_idx ? shu[2][w] : a.max_idx;
    }
    *slot = a;   // plain 32B store to this block's private slot
  }
  __syncthreads();  // shared arrays reused by the next scale's commit
}

// R3-proven structure: inline per-element pos handling. The extra mpos loads
// and predicated VALU are fully hidden under the memory stream (R3 vs R5/R6
// profiled identically); every attempt to "optimize" them (R4 split, R6
// phase, R7 __any gate) cost 5-20us of real overhead.
__device__ __forceinline__ void process_scale(
    const float* __restrict__ pred, const float* __restrict__ gt,
    const int* __restrict__ mpos, const int* __restrict__ mneg,
    u32 ngroups, u32 tid, u32 nthreads, ScaleAcc* __restrict__ slot)
{
  float sc = 0.f, sf = 0.f, sb = 0.f, sn = 0.f;
  u32 np = 0, nn = 0, mi = 0;
  const float4* p4 = (const float4*)pred;
  const float4* g4 = (const float4*)gt;
  const int4*   m4 = (const int4*)mneg;
  for (u32 g = tid; g < ngroups; g += nthreads) {
    float4 pv = p4[g];
    float4 gv = g4[g];
    int4   mv = m4[g];
    u32 base = g * 4u;
    u32 cell = base / 85u;           // compiler magic-mul
    u32 ch = base - cell * 85u;
    float ps[4] = {pv.x, pv.y, pv.z, pv.w};
    float gs[4] = {gv.x, gv.y, gv.z, gv.w};
    int   ms[4] = {mv.x, mv.y, mv.z, mv.w};
    #pragma unroll
    for (int j = 0; j < 4; ++j) {
      float x = ps[j], z = gs[j];
      float d = z - x;
      float d2 = d * d;
      if (ms[j]) { sn += d2; nn++; }
      if (mpos[cell]) {
        if (ch == 0u) { np++; mi = cell > mi ? cell : mi; }
        if (ch < 4u)        sc += d2;
        else if (ch == 4u)  sf += d2;
        else                sb += fmaxf(x, 0.f) - x * z + __logf(1.f + __expf(-fabsf(x)));
      }
      ++ch;
      if (ch == 85u) { ch = 0u; ++cell; }
    }
  }
  reduce_and_commit(sc, sf, sb, sn, np, nn, mi, slot);
}

__global__ __launch_bounds__(256) void yolo_main(
    const float* __restrict__ pred0, const float* __restrict__ gt0,
    const int* __restrict__ mp0, const int* __restrict__ mn0,
    const float* __restrict__ pred1, const float* __restrict__ gt1,
    const int* __restrict__ mp1, const int* __restrict__ mn1,
    const float* __restrict__ pred2, const float* __restrict__ gt2,
    const int* __restrict__ mp2, const int* __restrict__ mn2,
    ScaleAcc* __restrict__ ws)
{
  const u32 tid = blockIdx.x * blockDim.x + threadIdx.x;
  const u32 nthreads = gridDim.x * blockDim.x;
  process_scale(pred0, gt0, mp0, mn0, NE0 / 4u, tid, nthreads, &ws[0 * NBLK + blockIdx.x]);
  process_scale(pred1, gt1, mp1, mn1, NE1 / 4u, tid, nthreads, &ws[1 * NBLK + blockIdx.x]);
  process_scale(pred2, gt2, mp2, mn2, NE2 / 4u, tid, nthreads, &ws[2 * NBLK + blockIdx.x]);
}

// Single-block second stage: reduce 2048 partials/scale + finalize the loss.
__global__ __launch_bounds__(256) void yolo_reduce(
    const ScaleAcc* __restrict__ ws,
    const float* __restrict__ mod0, const float* __restrict__ mod1,
    const float* __restrict__ mod2, float* __restrict__ out)
{
  const float* mods[3] = {mod0, mod1, mod2};
  __shared__ float shf[4][4];
  __shared__ u32 shu[3][4];
  const int wave = threadIdx.x >> 6;
  const int lane = threadIdx.x & 63;
  float loss = 0.f;   // only thread 0's copy matters
  for (int s = 0; s < 3; ++s) {
    float sc = 0.f, sf = 0.f, sb = 0.f, sn = 0.f;
    u32 np = 0, nn = 0, mi = 0;
    for (u32 t = threadIdx.x; t < NBLK; t += 256u) {
      ScaleAcc a = ws[(u32)s * NBLK + t];
      sc += a.sum_coord; sf += a.sum_conf; sb += a.sum_bce; sn += a.sum_neg;
      np += a.n_pos; nn += a.n_neg;
      mi = a.max_idx > mi ? a.max_idx : mi;
    }
    #pragma unroll
    for (int o = 32; o > 0; o >>= 1) {
      sc += __shfl_down(sc, o);
      sf += __shfl_down(sf, o);
      sb += __shfl_down(sb, o);
      sn += __shfl_down(sn, o);
      np += __shfl_down(np, o);
      nn += __shfl_down(nn, o);
      u32 omi = __shfl_down(mi, o);
      mi = omi > mi ? omi : mi;
    }
    if (lane == 0) {
      shf[0][wave] = sc; shf[1][wave] = sf; shf[2][wave] = sb; shf[3][wave] = sn;
      shu[0][wave] = np; shu[1][wave] = nn; shu[2][wave] = mi;
    }
    __syncthreads();
    if (threadIdx.x == 0) {
      float a = 0.f, b = 0.f, c = 0.f, d = 0.f;
      u32 x = 0, y = 0, z = 0;
      #pragma unroll
      for (int w = 0; w < 4; ++w) {
        a += shf[0][w]; b += shf[1][w]; c += shf[2][w]; d += shf[3][w];
        x += shu[0][w]; y += shu[1][w];
        z = shu[2][w] > z ? shu[2][w] : z;
      }
      if (x > 0u) {
        float npf = (float)x;
        float w_last = mods[s][(size_t)z * 6u];  // modulus.reshape(-1,6)[idx_last,0]
        loss += (w_last * a + b + c * (1.f / 80.f)) / npf;
      }
      if (y > 0u) {
        loss += 3.0f * d / (float)y;
      }
    }
    __syncthreads();
  }
  if (threadIdx.x == 0) out[0] = loss;
}

extern "C" void kernel_launch(void* const* d_in, const int* in_sizes, int n_in,
                              void* d_out, int out_size, void* d_ws, size_t ws_size,
                              hipStream_t stream)
{
  const float* pred0 = (const float*)d_in[0];
  const float* gt0   = (const float*)d_in[1];
  const float* mod0  = (const float*)d_in[2];
  const int*   mp0   = (const int*)d_in[3];
  const int*   mn0   = (const int*)d_in[4];
  const float* pred1 = (const float*)d_in[5];
  const float* gt1   = (const float*)d_in[6];
  const float* mod1  = (const float*)d_in[7];
  const int*   mp1   = (const int*)d_in[8];
  const int*   mn1   = (const int*)d_in[9];
  const float* pred2 = (const float*)d_in[10];
  const float* gt2   = (const float*)d_in[11];
  const float* mod2  = (const float*)d_in[12];
  const int*   mp2   = (const int*)d_in[13];
  const int*   mn2   = (const int*)d_in[14];

  ScaleAcc* ws = (ScaleAcc*)d_ws;   // 3*2048*32B = 192 KB, every slot written

  yolo_main<<<NBLK, 256, 0, stream>>>(pred0, gt0, mp0, mn0,
                                      pred1, gt1, mp1, mn1,
                                      pred2, gt2, mp2, mn2, ws);
  yolo_reduce<<<1, 256, 0, stream>>>(ws, mod0, mod1, mod2, (float*)d_out);
}